// Round 2
// baseline (481.207 us; speedup 1.0000x reference)
//
#include <hip/hip_runtime.h>
#include <stdint.h>

// Problem constants (from reference):
constexpr int kB   = 8;
constexpr int kL1  = 1024;
constexpr int kC   = 128;
constexpr int kL2  = 256;
constexpr int kS   = 16;
constexpr int kNQ  = kB * kS;        // 128 queries
constexpr int kNDB = 8192;
constexpr float kEPS = 1e-8f;
constexpr int kRow = kC * kL2;       // 32768 floats per database row

constexpr int kTL2    = 32;           // l2 per LDS chunk
constexpr int kNCHUNK = kL2 / kTL2;   // 8
constexpr int kPAD    = 129;          // LDS tile pitch (l2-major, padded)

// ---------------------------------------------------------------------------
// Phase 0: gather-address table. addr = (l2 & 31)*129 + c, fits uint16.
// pos = f32(start) + f32(end-start)*((l2+0.5)/256)  -- mul then add, NO fma,
// matching jnp's separately-rounded ops.
// ---------------------------------------------------------------------------
__global__ void build_addr_kernel(const int* __restrict__ seq,
                                  const int* __restrict__ kp,
                                  uint16_t* __restrict__ addr16) {
    const int q  = blockIdx.x;    // 0..127
    const int l2 = threadIdx.x;   // 0..255
    const int b = q >> 4;
    const int s = q & 15;
    int start = kp[b * (kS + 1) + s];
    int end_  = kp[b * (kS + 1) + s + 1];
    if (end_ < start + 1) end_ = start + 1;
    const float frac = (l2 + 0.5f) * (1.0f / 256.0f);   // exact (pow2 divide)
    const float pos = __fadd_rn((float)start, __fmul_rn((float)(end_ - start), frac));
    int idx = (int)pos;                                  // trunc, pos >= 0
    idx = idx < 0 ? 0 : (idx > kL1 - 1 ? kL1 - 1 : idx);
    const int c = seq[b * kL1 + idx];
    addr16[q * kL2 + l2] = (uint16_t)((l2 & (kTL2 - 1)) * kPAD + c);
}

// ---------------------------------------------------------------------------
// Phase 1: one block per database row n (XCD-swizzled).
// Software-pipelined: chunk k+1's global loads are issued immediately after
// the stage barrier, so they fly during chunk k's LDS gather; the NEXT
// iteration's barrier vmcnt(0)-drain is exactly the wait we need before the
// LDS write. 8 chunks of 32 l2; LDS 17 KiB -> 8 blocks/CU (32 waves).
// ---------------------------------------------------------------------------
__launch_bounds__(256, 8)
__global__ void sim_kernel(const float* __restrict__ db,
                           const uint16_t* __restrict__ addr16,
                           float* __restrict__ sims) {
    __shared__ float tile[kTL2 * kPAD];   // 16,512 B
    __shared__ float accbuf[128];
    __shared__ float nsh[4];

    // XCD-aware swizzle: consecutive n (which share sims cache lines per q)
    // land on the same XCD so partial-line writes merge in one L2.
    const int bid = blockIdx.x;
    const int n   = (bid & 7) * (kNDB / 8) + (bid >> 3);

    const int t = threadIdx.x;
    const int q = t & 127;
    const int h = t >> 7;
    const float* rowp = db + (size_t)n * kRow;

    // Per-thread staging geometry (constant across chunks):
    //   j = (t + 256k)*4 flat float index in a 128c x 32l2 chunk
    //   c = j>>5, l2l = j&31  -> 8-lane groups read 128B contiguous. Coalesced.
    float4 buf[4];
    #pragma unroll
    for (int k = 0; k < 4; ++k) {
        const int j   = (t + 256 * k) * 4;
        const int c   = j >> 5;
        const int l2l = j & 31;
        buf[k] = *reinterpret_cast<const float4*>(rowp + c * kL2 + l2l);
    }

    float a0 = 0.f, a1 = 0.f, a2 = 0.f, a3 = 0.f;
    float nrm = 0.f;

    for (int chunk = 0; chunk < kNCHUNK; ++chunk) {
        if (chunk) __syncthreads();   // prior gathers done; buf loads drained

        // ---- write staged regs -> LDS (transposed, padded) + norm fma ----
        #pragma unroll
        for (int k = 0; k < 4; ++k) {
            const int j   = (t + 256 * k) * 4;
            const int c   = j >> 5;
            const int l2l = j & 31;
            const float4 v = buf[k];
            nrm = fmaf(v.x, v.x, nrm);
            nrm = fmaf(v.y, v.y, nrm);
            nrm = fmaf(v.z, v.z, nrm);
            nrm = fmaf(v.w, v.w, nrm);
            tile[(l2l + 0) * kPAD + c] = v.x;
            tile[(l2l + 1) * kPAD + c] = v.y;
            tile[(l2l + 2) * kPAD + c] = v.z;
            tile[(l2l + 3) * kPAD + c] = v.w;
        }
        __syncthreads();

        // ---- prefetch chunk+1 into regs (flies during the gather) ----
        if (chunk + 1 < kNCHUNK) {
            #pragma unroll
            for (int k = 0; k < 4; ++k) {
                const int j   = (t + 256 * k) * 4;
                const int c   = j >> 5;
                const int l2l = j & 31;
                buf[k] = *reinterpret_cast<const float4*>(
                    rowp + c * kL2 + (chunk + 1) * kTL2 + l2l);
            }
        }

        // ---- gather 16 elements for (q, h) from precomputed LDS addrs ----
        const uint16_t* ap = addr16 + q * kL2 + chunk * kTL2 + h * 16;
        #pragma unroll
        for (int g = 0; g < 2; ++g) {
            union { uint4 v; uint16_t u[8]; } pk;
            pk.v = *reinterpret_cast<const uint4*>(ap + g * 8);
            a0 += tile[pk.u[0]];
            a1 += tile[pk.u[1]];
            a2 += tile[pk.u[2]];
            a3 += tile[pk.u[3]];
            a0 += tile[pk.u[4]];
            a1 += tile[pk.u[5]];
            a2 += tile[pk.u[6]];
            a3 += tile[pk.u[7]];
        }
    }

    // ---- epilogue: wave-shuffle norm reduce + pairwise acc combine ----
    const float part = (a0 + a1) + (a2 + a3);
    #pragma unroll
    for (int off = 32; off > 0; off >>= 1) nrm += __shfl_down(nrm, off);
    if ((t & 63) == 0) nsh[t >> 6] = nrm;
    if (h) accbuf[q] = part;
    __syncthreads();
    if (!h) {
        const float total = part + accbuf[q];
        const float norm  = sqrtf((nsh[0] + nsh[1]) + (nsh[2] + nsh[3]));
        const float inv   = 1.0f / ((norm + kEPS) * (16.0f + kEPS));
        sims[(size_t)q * kNDB + n] = total * inv;
    }
}

// ---------------------------------------------------------------------------
// Phase 2: per-query argmax over 8192 (first-max tie-break = lowest index),
// predictions = float(db_classes[argmax]), unit_sim = max.
// ---------------------------------------------------------------------------
__global__ void argmax_kernel(const float* __restrict__ sims,
                              const int* __restrict__ db_classes,
                              float* __restrict__ preds,
                              float* __restrict__ unit) {
    const int q = blockIdx.x;
    const int t = threadIdx.x;
    const float* row = sims + (size_t)q * kNDB;

    float best = -1e30f;
    int bidx = kNDB;
    for (int n = t; n < kNDB; n += 256) {   // increasing n: '>' keeps first max
        const float v = row[n];
        if (v > best) { best = v; bidx = n; }
    }

    __shared__ float bv[256];
    __shared__ int   bi[256];
    bv[t] = best;
    bi[t] = bidx;
    __syncthreads();
    for (int s2 = 128; s2 > 0; s2 >>= 1) {
        if (t < s2) {
            const float ov = bv[t + s2];
            const int   oi = bi[t + s2];
            if (ov > bv[t] || (ov == bv[t] && oi < bi[t])) {
                bv[t] = ov;
                bi[t] = oi;
            }
        }
        __syncthreads();
    }
    if (t == 0) {
        preds[q] = (float)db_classes[bi[0]];
        unit[q]  = bv[0];
    }
}

// ---------------------------------------------------------------------------
extern "C" void kernel_launch(void* const* d_in, const int* in_sizes, int n_in,
                              void* d_out, int out_size, void* d_ws, size_t ws_size,
                              hipStream_t stream) {
    const int*   seq        = (const int*)d_in[0];     // (8, 1024) int32
    const int*   kp         = (const int*)d_in[1];     // (8, 17)   int32
    const float* db         = (const float*)d_in[2];   // (8192, 128, 256) f32
    const int*   db_classes = (const int*)d_in[3];     // (8192,)   int32

    float* out   = (float*)d_out;                 // sims | preds | unit_sim
    float* preds = out + (size_t)kNQ * kNDB;      // + 1048576
    float* unit  = preds + kNQ;                   // + 128

    uint16_t* addr16 = (uint16_t*)d_ws;           // 64 KiB scratch

    build_addr_kernel<<<kNQ, kL2, 0, stream>>>(seq, kp, addr16);
    sim_kernel<<<kNDB, 256, 0, stream>>>(db, addr16, out);
    argmax_kernel<<<kNQ, 256, 0, stream>>>(out, db_classes, preds, unit);
}

// Round 3
// 306.713 us; speedup vs baseline: 1.5689x; 1.5689x over previous
//
#include <hip/hip_runtime.h>
#include <stdint.h>

// Problem constants (from reference):
constexpr int kB   = 8;
constexpr int kL1  = 1024;
constexpr int kC   = 128;
constexpr int kL2  = 256;
constexpr int kS   = 16;
constexpr int kNQ  = kB * kS;        // 128 queries
constexpr int kNDB = 8192;
constexpr float kEPS = 1e-8f;
constexpr int kRow = kC * kL2;       // 32768 floats per database row

constexpr int kTL2    = 64;           // l2 per LDS chunk  (round-1 geometry)
constexpr int kNCHUNK = kL2 / kTL2;   // 4
constexpr int kPAD    = 129;          // LDS tile pitch (l2-major, padded)

// ---------------------------------------------------------------------------
// Phase 0: gather-address table. addr = (l2 & 63)*129 + c, fits uint16.
// pos = f32(start) + f32(end-start)*((l2+0.5)/256)  -- mul then add, NO fma,
// matching jnp's separately-rounded ops.
// ---------------------------------------------------------------------------
__global__ void build_addr_kernel(const int* __restrict__ seq,
                                  const int* __restrict__ kp,
                                  uint16_t* __restrict__ addr16) {
    const int q  = blockIdx.x;    // 0..127
    const int l2 = threadIdx.x;   // 0..255
    const int b = q >> 4;
    const int s = q & 15;
    int start = kp[b * (kS + 1) + s];
    int end_  = kp[b * (kS + 1) + s + 1];
    if (end_ < start + 1) end_ = start + 1;
    const float frac = (l2 + 0.5f) * (1.0f / 256.0f);   // exact (pow2 divide)
    const float pos = __fadd_rn((float)start, __fmul_rn((float)(end_ - start), frac));
    int idx = (int)pos;                                  // trunc, pos >= 0
    idx = idx < 0 ? 0 : (idx > kL1 - 1 ? kL1 - 1 : idx);
    const int c = seq[b * kL1 + idx];
    addr16[q * kL2 + l2] = (uint16_t)((l2 & (kTL2 - 1)) * kPAD + c);
}

// ---------------------------------------------------------------------------
// Phase 1: one block per database row n.
// Round-1 geometry (4 chunks of 64 l2, LDS 33 KiB, 4 blocks/CU, 128-VGPR
// budget) + T14 async-STAGE split: chunk k+1's 8 float4 loads are issued
// right after the write-visibility barrier so 32 KiB of global traffic is in
// flight during the whole gather phase. The dependency wait (vmcnt before the
// next chunk's ds_writes) lands after the next top barrier -- exactly where
// we'd have to wait anyway.
//   LDS tile transposed+padded: tile[l2l*129 + c].
//     writes: 64 lanes -> 32 banks x 2       -> conflict-free
//     gather reads: bank ~ (l2l + c) & 31, c random -> ~4-way worst case
// ---------------------------------------------------------------------------
__launch_bounds__(256, 4)
__global__ void sim_kernel(const float* __restrict__ db,
                           const uint16_t* __restrict__ addr16,
                           float* __restrict__ sims) {
    __shared__ float tile[kTL2 * kPAD];   // 33,024 B
    __shared__ float accbuf[128];
    __shared__ float nsh[4];

    const int n = blockIdx.x;
    const int t = threadIdx.x;
    const int q = t & 127;
    const int h = t >> 7;
    const float* rowp = db + (size_t)n * kRow;

    // Per-thread staging geometry (constant across chunks):
    //   j = (t + 256k)*4 flat float index in a 128c x 64l2 chunk
    //   c = j>>6, l2l = j&63 -> 16-lane groups read 256 B contiguous.
    float4 buf[8];                         // 32 VGPRs of prefetch state
    #pragma unroll
    for (int k = 0; k < 8; ++k) {
        const int j   = (t + 256 * k) * 4;
        const int c   = j >> 6;
        const int l2l = j & 63;
        buf[k] = *reinterpret_cast<const float4*>(rowp + c * kL2 + l2l);
    }

    float a0 = 0.f, a1 = 0.f, a2 = 0.f, a3 = 0.f;
    float nrm = 0.f;

    for (int chunk = 0; chunk < kNCHUNK; ++chunk) {
        if (chunk) __syncthreads();   // prior gathers done before overwrite

        // ---- write staged regs -> LDS (transposed, padded) + norm fma ----
        #pragma unroll
        for (int k = 0; k < 8; ++k) {
            const int j   = (t + 256 * k) * 4;
            const int c   = j >> 6;
            const int l2l = j & 63;
            const float4 v = buf[k];
            nrm = fmaf(v.x, v.x, nrm);
            nrm = fmaf(v.y, v.y, nrm);
            nrm = fmaf(v.z, v.z, nrm);
            nrm = fmaf(v.w, v.w, nrm);
            tile[(l2l + 0) * kPAD + c] = v.x;
            tile[(l2l + 1) * kPAD + c] = v.y;
            tile[(l2l + 2) * kPAD + c] = v.z;
            tile[(l2l + 3) * kPAD + c] = v.w;
        }
        __syncthreads();

        // ---- prefetch chunk+1 into regs (flies during the gather) ----
        if (chunk + 1 < kNCHUNK) {
            #pragma unroll
            for (int k = 0; k < 8; ++k) {
                const int j   = (t + 256 * k) * 4;
                const int c   = j >> 6;
                const int l2l = j & 63;
                buf[k] = *reinterpret_cast<const float4*>(
                    rowp + c * kL2 + (chunk + 1) * kTL2 + l2l);
            }
        }

        // ---- gather 32 elements for (q, h) from precomputed LDS addrs ----
        const uint16_t* ap = addr16 + q * kL2 + chunk * kTL2 + h * 32;
        #pragma unroll
        for (int g = 0; g < 4; ++g) {
            union { uint4 v; uint16_t u[8]; } pk;
            pk.v = *reinterpret_cast<const uint4*>(ap + g * 8);
            a0 += tile[pk.u[0]];
            a1 += tile[pk.u[1]];
            a2 += tile[pk.u[2]];
            a3 += tile[pk.u[3]];
            a0 += tile[pk.u[4]];
            a1 += tile[pk.u[5]];
            a2 += tile[pk.u[6]];
            a3 += tile[pk.u[7]];
        }
    }

    // ---- epilogue: wave-shuffle norm reduce + pairwise acc combine ----
    const float part = (a0 + a1) + (a2 + a3);
    #pragma unroll
    for (int off = 32; off > 0; off >>= 1) nrm += __shfl_down(nrm, off);
    if ((t & 63) == 0) nsh[t >> 6] = nrm;
    if (h) accbuf[q] = part;
    __syncthreads();
    if (!h) {
        const float total = part + accbuf[q];
        const float norm  = sqrtf((nsh[0] + nsh[1]) + (nsh[2] + nsh[3]));
        const float inv   = 1.0f / ((norm + kEPS) * (16.0f + kEPS));
        sims[(size_t)q * kNDB + n] = total * inv;
    }
}

// ---------------------------------------------------------------------------
// Phase 2: per-query argmax over 8192 (first-max tie-break = lowest index),
// predictions = float(db_classes[argmax]), unit_sim = max.
// ---------------------------------------------------------------------------
__global__ void argmax_kernel(const float* __restrict__ sims,
                              const int* __restrict__ db_classes,
                              float* __restrict__ preds,
                              float* __restrict__ unit) {
    const int q = blockIdx.x;
    const int t = threadIdx.x;
    const float* row = sims + (size_t)q * kNDB;

    float best = -1e30f;
    int bidx = kNDB;
    for (int n = t; n < kNDB; n += 256) {   // increasing n: '>' keeps first max
        const float v = row[n];
        if (v > best) { best = v; bidx = n; }
    }

    __shared__ float bv[256];
    __shared__ int   bi[256];
    bv[t] = best;
    bi[t] = bidx;
    __syncthreads();
    for (int s2 = 128; s2 > 0; s2 >>= 1) {
        if (t < s2) {
            const float ov = bv[t + s2];
            const int   oi = bi[t + s2];
            if (ov > bv[t] || (ov == bv[t] && oi < bi[t])) {
                bv[t] = ov;
                bi[t] = oi;
            }
        }
        __syncthreads();
    }
    if (t == 0) {
        preds[q] = (float)db_classes[bi[0]];
        unit[q]  = bv[0];
    }
}

// ---------------------------------------------------------------------------
extern "C" void kernel_launch(void* const* d_in, const int* in_sizes, int n_in,
                              void* d_out, int out_size, void* d_ws, size_t ws_size,
                              hipStream_t stream) {
    const int*   seq        = (const int*)d_in[0];     // (8, 1024) int32
    const int*   kp         = (const int*)d_in[1];     // (8, 17)   int32
    const float* db         = (const float*)d_in[2];   // (8192, 128, 256) f32
    const int*   db_classes = (const int*)d_in[3];     // (8192,)   int32

    float* out   = (float*)d_out;                 // sims | preds | unit_sim
    float* preds = out + (size_t)kNQ * kNDB;      // + 1048576
    float* unit  = preds + kNQ;                   // + 128

    uint16_t* addr16 = (uint16_t*)d_ws;           // 64 KiB scratch

    build_addr_kernel<<<kNQ, kL2, 0, stream>>>(seq, kp, addr16);
    sim_kernel<<<kNDB, 256, 0, stream>>>(db, addr16, out);
    argmax_kernel<<<kNQ, 256, 0, stream>>>(out, db_classes, preds, unit);
}

// Round 4
// 297.572 us; speedup vs baseline: 1.6171x; 1.0307x over previous
//
#include <hip/hip_runtime.h>
#include <stdint.h>

// Problem constants (from reference):
constexpr int kB   = 8;
constexpr int kL1  = 1024;
constexpr int kC   = 128;
constexpr int kL2  = 256;
constexpr int kS   = 16;
constexpr int kNQ  = kB * kS;        // 128 queries
constexpr int kNDB = 8192;
constexpr float kEPS = 1e-8f;
constexpr int kRow = kC * kL2;       // 32768 floats per database row

constexpr int kTL2    = 64;           // l2 per LDS chunk
constexpr int kNCHUNK = kL2 / kTL2;   // 4
constexpr int kPAD    = 129;          // LDS tile pitch (l2-major, padded)

// Raw barrier: LDS visibility via lgkmcnt(0), but NO vmcnt drain -- global
// loads stay in flight across the barrier (T4 / m201 pattern). The "memory"
// clobbers pin compile-time ordering of the LDS accesses around it.
#define BARRIER_LG()                                          \
    do {                                                      \
        asm volatile("s_waitcnt lgkmcnt(0)" ::: "memory");    \
        __builtin_amdgcn_s_barrier();                         \
        asm volatile("" ::: "memory");                        \
    } while (0)

// ---------------------------------------------------------------------------
// Phase 0: gather-address table. addr = (l2 & 63)*129 + c, fits uint16.
// pos = f32(start) + f32(end-start)*((l2+0.5)/256)  -- mul then add, NO fma,
// matching jnp's separately-rounded ops.
// ---------------------------------------------------------------------------
__global__ void build_addr_kernel(const int* __restrict__ seq,
                                  const int* __restrict__ kp,
                                  uint16_t* __restrict__ addr16) {
    const int q  = blockIdx.x;    // 0..127
    const int l2 = threadIdx.x;   // 0..255
    const int b = q >> 4;
    const int s = q & 15;
    int start = kp[b * (kS + 1) + s];
    int end_  = kp[b * (kS + 1) + s + 1];
    if (end_ < start + 1) end_ = start + 1;
    const float frac = (l2 + 0.5f) * (1.0f / 256.0f);   // exact (pow2 divide)
    const float pos = __fadd_rn((float)start, __fmul_rn((float)(end_ - start), frac));
    int idx = (int)pos;                                  // trunc, pos >= 0
    idx = idx < 0 ? 0 : (idx > kL1 - 1 ? kL1 - 1 : idx);
    const int c = seq[b * kL1 + idx];
    addr16[q * kL2 + l2] = (uint16_t)((l2 & (kTL2 - 1)) * kPAD + c);
}

// ---------------------------------------------------------------------------
// Phase 1 helpers (geometry identical to the verified round-1/3 kernel):
//   j = (t + 256k)*4 flat float index in a 128c x 64l2 chunk
//   c = j>>6, l2l = j&63 -> 16-lane groups read 256 B contiguous (coalesced).
// ---------------------------------------------------------------------------
__device__ __forceinline__ void stage_load(const float* __restrict__ rowp,
                                           int chunk, float4 (&buf)[8], int t) {
    #pragma unroll
    for (int k = 0; k < 8; ++k) {
        const int j   = (t + 256 * k) * 4;
        const int c   = j >> 6;
        const int l2l = j & 63;
        buf[k] = *reinterpret_cast<const float4*>(
            rowp + c * kL2 + chunk * kTL2 + l2l);
    }
}

__device__ __forceinline__ void stage_write(float* tile, const float4 (&buf)[8],
                                            int t, float& nrm) {
    #pragma unroll
    for (int k = 0; k < 8; ++k) {
        const int j   = (t + 256 * k) * 4;
        const int c   = j >> 6;
        const int l2l = j & 63;
        const float4 v = buf[k];
        nrm = fmaf(v.x, v.x, nrm);
        nrm = fmaf(v.y, v.y, nrm);
        nrm = fmaf(v.z, v.z, nrm);
        nrm = fmaf(v.w, v.w, nrm);
        tile[(l2l + 0) * kPAD + c] = v.x;
        tile[(l2l + 1) * kPAD + c] = v.y;
        tile[(l2l + 2) * kPAD + c] = v.z;
        tile[(l2l + 3) * kPAD + c] = v.w;
    }
}

__device__ __forceinline__ void gather32(const float* tile,
                                         const uint16_t* __restrict__ ap,
                                         float& a0, float& a1, float& a2, float& a3) {
    #pragma unroll
    for (int g = 0; g < 4; ++g) {
        union { uint4 v; uint16_t u[8]; } pk;
        pk.v = *reinterpret_cast<const uint4*>(ap + g * 8);
        a0 += tile[pk.u[0]];
        a1 += tile[pk.u[1]];
        a2 += tile[pk.u[2]];
        a3 += tile[pk.u[3]];
        a0 += tile[pk.u[4]];
        a1 += tile[pk.u[5]];
        a2 += tile[pk.u[6]];
        a3 += tile[pk.u[7]];
    }
}

// ---------------------------------------------------------------------------
// Phase 1: one block per database row n. 2-deep register double-buffer
// (bufA/bufB) + raw lgkm-only barriers: at every instant >= 8 float4 loads
// per thread-pair are outstanding, so HBM never idles during write/gather/
// barrier phases. Each stage_write's vmcnt dependency is counted (waits only
// for its own buffer), inserted automatically by the compiler.
// ---------------------------------------------------------------------------
__launch_bounds__(256, 4)
__global__ void sim_kernel(const float* __restrict__ db,
                           const uint16_t* __restrict__ addr16,
                           float* __restrict__ sims) {
    __shared__ float tile[kTL2 * kPAD];   // 33,024 B
    __shared__ float accbuf[128];
    __shared__ float nsh[4];

    const int n = blockIdx.x;
    const int t = threadIdx.x;
    const int q = t & 127;
    const int h = t >> 7;
    const float* rowp = db + (size_t)n * kRow;
    const uint16_t* aq = addr16 + q * kL2 + h * 32;

    float4 bufA[8], bufB[8];              // 64 VGPRs of prefetch state
    stage_load(rowp, 0, bufA, t);
    stage_load(rowp, 1, bufB, t);

    float a0 = 0.f, a1 = 0.f, a2 = 0.f, a3 = 0.f;
    float nrm = 0.f;

    // ---- chunk 0 (bufA) ----
    stage_write(tile, bufA, t, nrm);      // vmcnt waits only for bufA
    stage_load(rowp, 2, bufA, t);         // refill A; flies across barriers
    BARRIER_LG();
    gather32(tile, aq + 0 * kTL2, a0, a1, a2, a3);

    // ---- chunk 1 (bufB) ----
    BARRIER_LG();                         // gathers of chunk 0 done
    stage_write(tile, bufB, t, nrm);
    stage_load(rowp, 3, bufB, t);
    BARRIER_LG();
    gather32(tile, aq + 1 * kTL2, a0, a1, a2, a3);

    // ---- chunk 2 (bufA) ----
    BARRIER_LG();
    stage_write(tile, bufA, t, nrm);
    BARRIER_LG();
    gather32(tile, aq + 2 * kTL2, a0, a1, a2, a3);

    // ---- chunk 3 (bufB) ----
    BARRIER_LG();
    stage_write(tile, bufB, t, nrm);
    BARRIER_LG();
    gather32(tile, aq + 3 * kTL2, a0, a1, a2, a3);

    // ---- epilogue: wave-shuffle norm reduce + pairwise acc combine ----
    const float part = (a0 + a1) + (a2 + a3);
    float nw = nrm;
    #pragma unroll
    for (int off = 32; off > 0; off >>= 1) nw += __shfl_down(nw, off);
    if ((t & 63) == 0) nsh[t >> 6] = nw;
    if (h) accbuf[q] = part;
    BARRIER_LG();
    if (!h) {
        const float total = part + accbuf[q];
        const float norm  = sqrtf((nsh[0] + nsh[1]) + (nsh[2] + nsh[3]));
        const float inv   = 1.0f / ((norm + kEPS) * (16.0f + kEPS));
        sims[(size_t)q * kNDB + n] = total * inv;
    }
}

// ---------------------------------------------------------------------------
// Phase 2: per-query argmax over 8192 (first-max tie-break = lowest index),
// predictions = float(db_classes[argmax]), unit_sim = max.
// ---------------------------------------------------------------------------
__global__ void argmax_kernel(const float* __restrict__ sims,
                              const int* __restrict__ db_classes,
                              float* __restrict__ preds,
                              float* __restrict__ unit) {
    const int q = blockIdx.x;
    const int t = threadIdx.x;
    const float* row = sims + (size_t)q * kNDB;

    float best = -1e30f;
    int bidx = kNDB;
    for (int n = t; n < kNDB; n += 256) {   // increasing n: '>' keeps first max
        const float v = row[n];
        if (v > best) { best = v; bidx = n; }
    }

    __shared__ float bv[256];
    __shared__ int   bi[256];
    bv[t] = best;
    bi[t] = bidx;
    __syncthreads();
    for (int s2 = 128; s2 > 0; s2 >>= 1) {
        if (t < s2) {
            const float ov = bv[t + s2];
            const int   oi = bi[t + s2];
            if (ov > bv[t] || (ov == bv[t] && oi < bi[t])) {
                bv[t] = ov;
                bi[t] = oi;
            }
        }
        __syncthreads();
    }
    if (t == 0) {
        preds[q] = (float)db_classes[bi[0]];
        unit[q]  = bv[0];
    }
}

// ---------------------------------------------------------------------------
extern "C" void kernel_launch(void* const* d_in, const int* in_sizes, int n_in,
                              void* d_out, int out_size, void* d_ws, size_t ws_size,
                              hipStream_t stream) {
    const int*   seq        = (const int*)d_in[0];     // (8, 1024) int32
    const int*   kp         = (const int*)d_in[1];     // (8, 17)   int32
    const float* db         = (const float*)d_in[2];   // (8192, 128, 256) f32
    const int*   db_classes = (const int*)d_in[3];     // (8192,)   int32

    float* out   = (float*)d_out;                 // sims | preds | unit_sim
    float* preds = out + (size_t)kNQ * kNDB;      // + 1048576
    float* unit  = preds + kNQ;                   // + 128

    uint16_t* addr16 = (uint16_t*)d_ws;           // 64 KiB scratch

    build_addr_kernel<<<kNQ, kL2, 0, stream>>>(seq, kp, addr16);
    sim_kernel<<<kNDB, 256, 0, stream>>>(db, addr16, out);
    argmax_kernel<<<kNQ, 256, 0, stream>>>(out, db_classes, preds, unit);
}

// Round 5
// 230.170 us; speedup vs baseline: 2.0907x; 1.2928x over previous
//
#include <hip/hip_runtime.h>
#include <stdint.h>

// Problem constants (from reference):
constexpr int kB   = 8;
constexpr int kL1  = 1024;
constexpr int kC   = 128;
constexpr int kL2  = 256;
constexpr int kS   = 16;
constexpr int kNQ  = kB * kS;        // 128 queries
constexpr int kNDB = 8192;
constexpr float kEPS = 1e-8f;
constexpr int kRow = kC * kL2;       // 32768 floats per database row

constexpr int kTL2 = 64;             // l2 per LDS chunk (4 chunks per row)
constexpr int kPAD = 129;            // LDS tile pitch (l2-major, padded)

// Raw barrier: LDS visibility via lgkmcnt(0), NO vmcnt drain -- global loads
// stay in flight across it (T4 pattern, correctness proven in round 4).
#define BARRIER_LG()                                          \
    do {                                                      \
        asm volatile("s_waitcnt lgkmcnt(0)" ::: "memory");    \
        __builtin_amdgcn_s_barrier();                         \
        asm volatile("" ::: "memory");                        \
    } while (0)

// ---------------------------------------------------------------------------
// Phase 0: gather-address table. Stores BYTE offsets: ((l2&63)*129 + c)*4,
// max 33016 < 65536, fits uint16. pos = f32(start) + f32(end-start)*
// ((l2+0.5)/256) -- mul then add, NO fma, matching jnp's rounding.
// ---------------------------------------------------------------------------
__global__ void build_addr_kernel(const int* __restrict__ seq,
                                  const int* __restrict__ kp,
                                  uint16_t* __restrict__ addr16) {
    const int q  = blockIdx.x;    // 0..127
    const int l2 = threadIdx.x;   // 0..255
    const int b = q >> 4;
    const int s = q & 15;
    int start = kp[b * (kS + 1) + s];
    int end_  = kp[b * (kS + 1) + s + 1];
    if (end_ < start + 1) end_ = start + 1;
    const float frac = (l2 + 0.5f) * (1.0f / 256.0f);   // exact (pow2 divide)
    const float pos = __fadd_rn((float)start, __fmul_rn((float)(end_ - start), frac));
    int idx = (int)pos;                                  // trunc, pos >= 0
    idx = idx < 0 ? 0 : (idx > kL1 - 1 ? kL1 - 1 : idx);
    const int c = seq[b * kL1 + idx];
    addr16[q * kL2 + l2] = (uint16_t)((((l2 & (kTL2 - 1)) * kPAD) + c) * 4);
}

// ---------------------------------------------------------------------------
// Producer helpers. Staging geometry (t in [0,256)):
//   j = (t + 256k)*4 flat float index in a 128c x 64l2 chunk
//   c = j>>6, l2l = j&63 -> 16-lane groups read 256 B contiguous (coalesced).
// LDS tile transposed+padded: tile[l2l*129 + c]; writes are 2 lanes/bank
// (free), gather reads spread by random c over all 32 banks.
// ---------------------------------------------------------------------------
__device__ __forceinline__ void stage_load(const float* __restrict__ rowp,
                                           int chunk, float4 (&buf)[8], int t) {
    #pragma unroll
    for (int k = 0; k < 8; ++k) {
        const int j   = (t + 256 * k) * 4;
        const int c   = j >> 6;
        const int l2l = j & 63;
        buf[k] = *reinterpret_cast<const float4*>(
            rowp + c * kL2 + chunk * kTL2 + l2l);
    }
}

__device__ __forceinline__ void stage_write(float* tile, const float4 (&buf)[8],
                                            int t, float& nrm) {
    #pragma unroll
    for (int k = 0; k < 8; ++k) {
        const int j   = (t + 256 * k) * 4;
        const int c   = j >> 6;
        const int l2l = j & 63;
        const float4 v = buf[k];
        nrm = fmaf(v.x, v.x, nrm);
        nrm = fmaf(v.y, v.y, nrm);
        nrm = fmaf(v.z, v.z, nrm);
        nrm = fmaf(v.w, v.w, nrm);
        tile[(l2l + 0) * kPAD + c] = v.x;
        tile[(l2l + 1) * kPAD + c] = v.y;
        tile[(l2l + 2) * kPAD + c] = v.z;
        tile[(l2l + 3) * kPAD + c] = v.w;
    }
}

// Consumer helper: 32 gathers from precomputed BYTE offsets.
__device__ __forceinline__ void gather32(const float* tile,
                                         const uint16_t* __restrict__ ap,
                                         float& a0, float& a1, float& a2, float& a3) {
    const char* tb = (const char*)tile;
    #pragma unroll
    for (int g = 0; g < 4; ++g) {
        union { uint4 v; uint16_t u[8]; } pk;
        pk.v = *reinterpret_cast<const uint4*>(ap + g * 8);
        a0 += *(const float*)(tb + pk.u[0]);
        a1 += *(const float*)(tb + pk.u[1]);
        a2 += *(const float*)(tb + pk.u[2]);
        a3 += *(const float*)(tb + pk.u[3]);
        a0 += *(const float*)(tb + pk.u[4]);
        a1 += *(const float*)(tb + pk.u[5]);
        a2 += *(const float*)(tb + pk.u[6]);
        a3 += *(const float*)(tb + pk.u[7]);
    }
}

// ---------------------------------------------------------------------------
// Phase 1: one 512-thread block per database row n.
// Waves 0-3 (t<256): PRODUCERS -- stream the row through regs (fused norm fma)
//   into ping-pong LDS tiles; always have >=1 chunk of global loads in flight.
// Waves 4-7 (t>=256): CONSUMERS -- gather-only from the tile the producers
//   filled last phase. VMEM issue and LDS gather now overlap by construction
//   instead of alternating: wall time = max(HBM, LDS) not sum.
// 5 lgkm-only barriers on BOTH paths (wave-aligned branch -> legal pairing):
//   BAR1: T0(c0) ready | BAR2: T1(c1) ready & T0 drained | BAR3: T0(c2) ready
//   & T1 drained | BAR4: T1(c3) ready | BAR5: norm + partials visible.
// LDS 66.6 KiB -> 2 blocks/CU (16 waves). launch_bounds(512,2) -> 256 VGPR.
// ---------------------------------------------------------------------------
__launch_bounds__(512, 2)
__global__ void sim_kernel(const float* __restrict__ db,
                           const uint16_t* __restrict__ addr16,
                           float* __restrict__ sims) {
    __shared__ float tileA[kTL2 * kPAD];   // 33,024 B
    __shared__ float tileB[kTL2 * kPAD];   // 33,024 B
    __shared__ float accbuf[128];
    __shared__ float nsh[4];

    const int n = blockIdx.x;
    const int t = threadIdx.x;
    const float* rowp = db + (size_t)n * kRow;

    if (t < 256) {
        // ================= PRODUCER =================
        float4 bufA[8], bufB[8];
        stage_load(rowp, 0, bufA, t);
        stage_load(rowp, 1, bufB, t);
        float nrm = 0.f;

        stage_write(tileA, bufA, t, nrm);   // waits vmcnt for bufA only
        stage_load(rowp, 2, bufA, t);       // refill; flies across barriers
        BARRIER_LG();                       // BAR1: T0 ready

        stage_write(tileB, bufB, t, nrm);
        stage_load(rowp, 3, bufB, t);
        BARRIER_LG();                       // BAR2: T1 ready, T0 drained

        stage_write(tileA, bufA, t, nrm);
        BARRIER_LG();                       // BAR3: T0 ready, T1 drained

        stage_write(tileB, bufB, t, nrm);
        BARRIER_LG();                       // BAR4: T1 ready

        // norm reduce while consumers drain the last tile
        float nw = nrm;
        #pragma unroll
        for (int off = 32; off > 0; off >>= 1) nw += __shfl_down(nw, off);
        if ((t & 63) == 0) nsh[t >> 6] = nw;
        BARRIER_LG();                       // BAR5: nsh + accbuf visible
    } else {
        // ================= CONSUMER =================
        const int u = t - 256;
        const int q = u & 127;
        const int h = u >> 7;
        const uint16_t* aq = addr16 + q * kL2 + h * 32;

        float a0 = 0.f, a1 = 0.f, a2 = 0.f, a3 = 0.f;

        BARRIER_LG();                       // BAR1
        gather32(tileA, aq + 0 * kTL2, a0, a1, a2, a3);
        BARRIER_LG();                       // BAR2
        gather32(tileB, aq + 1 * kTL2, a0, a1, a2, a3);
        BARRIER_LG();                       // BAR3
        gather32(tileA, aq + 2 * kTL2, a0, a1, a2, a3);
        BARRIER_LG();                       // BAR4
        gather32(tileB, aq + 3 * kTL2, a0, a1, a2, a3);

        const float part = (a0 + a1) + (a2 + a3);
        if (h) accbuf[q] = part;
        BARRIER_LG();                       // BAR5

        if (!h) {
            const float total = part + accbuf[q];
            const float norm  = sqrtf((nsh[0] + nsh[1]) + (nsh[2] + nsh[3]));
            const float inv   = 1.0f / ((norm + kEPS) * (16.0f + kEPS));
            sims[(size_t)q * kNDB + n] = total * inv;
        }
    }
}

// ---------------------------------------------------------------------------
// Phase 2: per-query argmax over 8192 (first-max tie-break = lowest index),
// predictions = float(db_classes[argmax]), unit_sim = max.
// ---------------------------------------------------------------------------
__global__ void argmax_kernel(const float* __restrict__ sims,
                              const int* __restrict__ db_classes,
                              float* __restrict__ preds,
                              float* __restrict__ unit) {
    const int q = blockIdx.x;
    const int t = threadIdx.x;
    const float* row = sims + (size_t)q * kNDB;

    float best = -1e30f;
    int bidx = kNDB;
    for (int n = t; n < kNDB; n += 256) {   // increasing n: '>' keeps first max
        const float v = row[n];
        if (v > best) { best = v; bidx = n; }
    }

    __shared__ float bv[256];
    __shared__ int   bi[256];
    bv[t] = best;
    bi[t] = bidx;
    __syncthreads();
    for (int s2 = 128; s2 > 0; s2 >>= 1) {
        if (t < s2) {
            const float ov = bv[t + s2];
            const int   oi = bi[t + s2];
            if (ov > bv[t] || (ov == bv[t] && oi < bi[t])) {
                bv[t] = ov;
                bi[t] = oi;
            }
        }
        __syncthreads();
    }
    if (t == 0) {
        preds[q] = (float)db_classes[bi[0]];
        unit[q]  = bv[0];
    }
}

// ---------------------------------------------------------------------------
extern "C" void kernel_launch(void* const* d_in, const int* in_sizes, int n_in,
                              void* d_out, int out_size, void* d_ws, size_t ws_size,
                              hipStream_t stream) {
    const int*   seq        = (const int*)d_in[0];     // (8, 1024) int32
    const int*   kp         = (const int*)d_in[1];     // (8, 17)   int32
    const float* db         = (const float*)d_in[2];   // (8192, 128, 256) f32
    const int*   db_classes = (const int*)d_in[3];     // (8192,)   int32

    float* out   = (float*)d_out;                 // sims | preds | unit_sim
    float* preds = out + (size_t)kNQ * kNDB;      // + 1048576
    float* unit  = preds + kNQ;                   // + 128

    uint16_t* addr16 = (uint16_t*)d_ws;           // 64 KiB scratch

    build_addr_kernel<<<kNQ, kL2, 0, stream>>>(seq, kp, addr16);
    sim_kernel<<<kNDB, 512, 0, stream>>>(db, addr16, out);
    argmax_kernel<<<kNQ, 256, 0, stream>>>(out, db_classes, preds, unit);
}